// Round 5
// baseline (1986.026 us; speedup 1.0000x reference)
//
#include <hip/hip_runtime.h>
#include <hip/hip_bf16.h>

// Fused LayerNorm + QKV projection for B=4, S=2048, H=2048 (fp32 in/out).
//
// Round 5 (= round 4 resubmitted after infra failure): 256x256 tile, BK=32,
// 64 KiB LDS double-buffer -> 2 blocks/CU. Cross-block TLP fills the
// per-phase ds_read/barrier windows that limited round 3 (1 block/CU,
// MfmaUtil 35%). Counted vmcnt(2) per K-tile, raw s_barrier, setprio around
// MFMA, bijective XCD swizzle (768 % 8 == 0).

#define HD   2048            // hidden dim (K)
#define MTOT 8192            // B*S rows
#define NTOT 6144            // 3*H packed output cols
#define NKT  64              // K-tiles of BK=32

typedef __attribute__((ext_vector_type(8))) _Float16 f16x8;   // 4 VGPR
typedef __attribute__((ext_vector_type(4))) _Float16 f16x4;
typedef __attribute__((ext_vector_type(4))) float f32x4;

// ---------------------------------------------------------------------------
// Kernel 1: LayerNorm -> fp16.  One block per row, 256 threads, 8 elems each.
// ---------------------------------------------------------------------------
__global__ __launch_bounds__(256) void ln_f16_kernel(
    const float* __restrict__ x, const float* __restrict__ gamma,
    const float* __restrict__ beta, _Float16* __restrict__ hi) {
  const int row = blockIdx.x;
  const float* xr = x + (size_t)row * HD;
  const int t = threadIdx.x;

  float4 v0 = reinterpret_cast<const float4*>(xr)[t * 2];
  float4 v1 = reinterpret_cast<const float4*>(xr)[t * 2 + 1];
  float xs[8] = {v0.x, v0.y, v0.z, v0.w, v1.x, v1.y, v1.z, v1.w};

  float s = 0.f, q = 0.f;
#pragma unroll
  for (int j = 0; j < 8; ++j) { s += xs[j]; q += xs[j] * xs[j]; }
#pragma unroll
  for (int off = 32; off; off >>= 1) {
    s += __shfl_down(s, off);
    q += __shfl_down(q, off);
  }
  __shared__ float red[8];
  const int wid = t >> 6, lane = t & 63;
  if (lane == 0) { red[wid] = s; red[4 + wid] = q; }
  __syncthreads();
  s = red[0] + red[1] + red[2] + red[3];
  q = red[4] + red[5] + red[6] + red[7];
  const float mu  = s * (1.f / HD);
  const float var = q * (1.f / HD) - mu * mu;
  const float rs  = rsqrtf(var + 1e-5f);

  float4 g0 = reinterpret_cast<const float4*>(gamma)[t * 2];
  float4 g1 = reinterpret_cast<const float4*>(gamma)[t * 2 + 1];
  float4 b0 = reinterpret_cast<const float4*>(beta)[t * 2];
  float4 b1 = reinterpret_cast<const float4*>(beta)[t * 2 + 1];
  float gs[8] = {g0.x, g0.y, g0.z, g0.w, g1.x, g1.y, g1.z, g1.w};
  float bs[8] = {b0.x, b0.y, b0.z, b0.w, b1.x, b1.y, b1.z, b1.w};

  f16x8 hv;
#pragma unroll
  for (int j = 0; j < 8; ++j) {
    float y = (xs[j] - mu) * rs * gs[j] + bs[j];
    hv[j] = (_Float16)y;
  }
  *reinterpret_cast<f16x8*>(&hi[(size_t)row * HD + t * 8]) = hv;
}

// ---------------------------------------------------------------------------
// Kernel 2: weights -> fp16 (q, k, v stacked).
// ---------------------------------------------------------------------------
__global__ __launch_bounds__(256) void w_f16_kernel(
    const float* __restrict__ qw, const float* __restrict__ kw,
    const float* __restrict__ vw, _Float16* __restrict__ hi) {
  const int m = blockIdx.y;
  const float* src = (m == 0) ? qw : (m == 1) ? kw : vw;
  const size_t base = (size_t)m * HD * HD;
  const int total4 = HD * HD / 4;
  for (int i = blockIdx.x * blockDim.x + threadIdx.x; i < total4;
       i += gridDim.x * blockDim.x) {
    float4 v = reinterpret_cast<const float4*>(src)[i];
    f16x4 hv;
    hv[0] = (_Float16)v.x; hv[1] = (_Float16)v.y;
    hv[2] = (_Float16)v.z; hv[3] = (_Float16)v.w;
    *reinterpret_cast<f16x4*>(&hi[base + (size_t)i * 4]) = hv;
  }
}

// ---------------------------------------------------------------------------
// Kernel 3: 256x256 fp16 GEMM, BK=32, 2 blocks/CU.
// out[m][n] = sum_k A[m][k] * W_p[n][k] + bias_p[n]
//
// LDS (64 KiB, f16 units): buf b at b*16384: A-plane [4kb][256][8] at +0,
// B-plane at +8192.  Chunk (kb,row) holds X[row][kt*32 + kb*8 .. +8]:
// linear for global_load_lds, conflict-free ds_read_b128.
//
// Phases (2 per K-tile j, buf = j&1):
//   a(j): BLOAD(4) + ALOAD mh0 (4); stage stA(j+1 -> buf j+1&1);
//         BAR; lgkm0; 16 MFMA; BAR
//   b(j): ALOAD mh1 (4); stage stB(j+2 -> buf j&1);
//         BAR; lgkm0; 16 MFMA; vmcnt(2); BAR
// Ledger: at b(j)'s vmcnt(2), outstanding worst-case = {stB(j+1) [drained by
// prev wait], stA(j+1), stB(j+2)}; waiting to <=2 guarantees stB(j+1) and
// stA(j+1) landed = exactly buf(j+1)'s content, with stB(j+2) in flight.
// Write-side safety: stA(j+1) overwrites A-plane last read at b(j-1) (before
// its trailing barrier); stB(j+2) overwrites B-plane last read at a(j).
// ---------------------------------------------------------------------------
__device__ __forceinline__ void gload16(const _Float16* g, _Float16* l) {
  __builtin_amdgcn_global_load_lds(
      (const __attribute__((address_space(1))) void*)g,
      (__attribute__((address_space(3))) void*)l, 16, 0, 0);
}

#define BAR()   asm volatile("s_barrier" ::: "memory")
#define LGKM0() asm volatile("s_waitcnt lgkmcnt(0)" ::: "memory")
#define VM2()   asm volatile("s_waitcnt vmcnt(2)" ::: "memory")
#define VM0()   asm volatile("s_waitcnt vmcnt(0)" ::: "memory")

#define LA(BUF, MR) \
  (*(const f16x8*)(lds + (BUF)*16384 + rA + (MR)*128))
#define LB(BUF, NR) \
  (*(const f16x8*)(lds + (BUF)*16384 + 8192 + rB + (NR)*128))

#define BLOAD(BUF) do { \
    bfr[0]=LB(BUF,0); bfr[1]=LB(BUF,1); bfr[2]=LB(BUF,2); bfr[3]=LB(BUF,3); \
  } while (0)
#define ALOAD(BUF, MH) do { \
    a0=LA(BUF,(MH)*4+0); a1=LA(BUF,(MH)*4+1); \
    a2=LA(BUF,(MH)*4+2); a3=LA(BUF,(MH)*4+3); \
  } while (0)

#define MM(MR, NR, AREG) \
  acc[MR][NR] = __builtin_amdgcn_mfma_f32_16x16x32_f16( \
      AREG, bfr[NR], acc[MR][NR], 0, 0, 0);
#define MFMAS(MH) do { \
    __builtin_amdgcn_s_setprio(1); \
    MM((MH)*4+0, 0, a0) MM((MH)*4+0, 1, a0) MM((MH)*4+0, 2, a0) MM((MH)*4+0, 3, a0) \
    MM((MH)*4+1, 0, a1) MM((MH)*4+1, 1, a1) MM((MH)*4+1, 2, a1) MM((MH)*4+1, 3, a1) \
    MM((MH)*4+2, 0, a2) MM((MH)*4+2, 1, a2) MM((MH)*4+2, 2, a2) MM((MH)*4+2, 3, a2) \
    MM((MH)*4+3, 0, a3) MM((MH)*4+3, 1, a3) MM((MH)*4+3, 2, a3) MM((MH)*4+3, 3, a3) \
    __builtin_amdgcn_s_setprio(0); \
  } while (0)

#define MIDBAR() do { BAR(); LGKM0(); __builtin_amdgcn_sched_barrier(0); } while (0)

__global__ __launch_bounds__(512, 4) void qkv_gemm_kernel(
    const _Float16* __restrict__ Ah, const _Float16* __restrict__ Wh,
    const float* __restrict__ qb, const float* __restrict__ kb,
    const float* __restrict__ vb, float* __restrict__ out) {
  extern __shared__ _Float16 lds[];   // 65536 B

  const int t    = threadIdx.x;
  const int lane = t & 63;
  const int wid  = t >> 6;            // 0..7
  const int wm   = wid >> 2;          // 0..1 (M)
  const int wn   = wid & 3;           // 0..3 (N)
  const int fr   = lane & 15;
  const int fq   = lane >> 4;

  // Bijective XCD swizzle: 768 workgroups, 96 per XCD (4 contiguous rows of
  // 24 -> each XCD's 4 A-panels fit its 4 MiB private L2).
  const int orig = blockIdx.y * gridDim.x + blockIdx.x;
  const int wg   = (orig & 7) * 96 + (orig >> 3);
  const int bx   = wg % 24;
  const int by   = wg / 24;

  const int n0  = bx * 256;
  const int m0  = by * 256;
  const int p   = n0 >> 11;
  const int ln0 = n0 & (HD - 1);
  const _Float16* Ag = Ah + (size_t)m0 * HD;
  const _Float16* Bg = Wh + (size_t)p * HD * HD + (size_t)ln0 * HD;
  const float* bias = (p == 0) ? qb : (p == 1) ? kb : vb;

  // Staging invariants: chunk c = kb0*256 + row (row = t&255, kb0 = t>>8);
  // second gload covers kb0+2 (LDS +4096 f16, global +16 f16).
  const int row  = t & 255;
  const int kb0  = t >> 8;                          // 0..1
  const int cOfs = kb0 * 256 + row;
  const size_t gOfs = (size_t)row * HD + kb0 * 8;

  // Fragment-read invariants (f16 offsets within a buffer).
  const int rA = fq * 2048 + wm * 1024 + fr * 8;
  const int rB = fq * 2048 + wn * 512 + fr * 8;

  auto stA = [&](int buf, int kt) {
    const _Float16* g = Ag + gOfs + kt * 32;
    _Float16* l = lds + buf * 16384 + cOfs * 8;
    gload16(g, l); gload16(g + 16, l + 4096);
  };
  auto stB = [&](int buf, int kt) {
    const _Float16* g = Bg + gOfs + kt * 32;
    _Float16* l = lds + buf * 16384 + 8192 + cOfs * 8;
    gload16(g, l); gload16(g + 16, l + 4096);
  };

  f32x4 acc[8][4] = {};

  // Prologue: B0, A0 (buf0), B1 (buf1).  vmcnt(2) -> B0+A0 landed.
  stB(0, 0); stA(0, 0); stB(1, 1);
  VM2();
  BAR();

#pragma unroll 1
  for (int i = 0; i < NKT / 2; ++i) {
    const int kt0 = 2 * i, kt1 = 2 * i + 1;
    const bool nl = (i < NKT / 2 - 1);
    f16x8 bfr[4];
    f16x8 a0, a1, a2, a3;

    // ---- a(kt0): buf0 ----
    BLOAD(0); ALOAD(0, 0);
    stA(1, kt0 + 1);                       // kt0+1 <= 63 always
    MIDBAR(); MFMAS(0); BAR();

    // ---- b(kt0) ----
    ALOAD(0, 1);
    if (nl) stB(0, kt0 + 2);
    MIDBAR(); MFMAS(1);
    if (nl) { VM2(); } else { VM0(); }     // buf1 content landed
    BAR();

    // ---- a(kt1): buf1 ----
    BLOAD(1); ALOAD(1, 0);
    if (nl) stA(0, kt1 + 1);
    MIDBAR(); MFMAS(0); BAR();

    // ---- b(kt1) ----
    ALOAD(1, 1);
    if (nl) stB(1, kt1 + 2);
    MIDBAR(); MFMAS(1);
    if (nl) { VM2(); }                     // buf0 content landed
    BAR();
  }

  // Epilogue: C/D layout col = lane&15, row = (lane>>4)*4 + reg.
  float bv[4];
#pragma unroll
  for (int nr = 0; nr < 4; ++nr)
    bv[nr] = bias[(ln0 + wn * 64 + nr * 16 + fr)];
#pragma unroll
  for (int mr = 0; mr < 8; ++mr) {
    const int r0 = m0 + wm * 128 + mr * 16 + fq * 4;
#pragma unroll
    for (int nr = 0; nr < 4; ++nr) {
      const int cg = n0 + wn * 64 + nr * 16 + fr;
      f32x4 v = acc[mr][nr];
#pragma unroll
      for (int r = 0; r < 4; ++r)
        out[(size_t)(r0 + r) * NTOT + cg] = v[r] + bv[nr];
    }
  }
}

// ---------------------------------------------------------------------------
extern "C" void kernel_launch(void* const* d_in, const int* in_sizes, int n_in,
                              void* d_out, int out_size, void* d_ws,
                              size_t ws_size, hipStream_t stream) {
  const float* x     = (const float*)d_in[0];
  const float* gamma = (const float*)d_in[1];
  const float* beta  = (const float*)d_in[2];
  const float* qw    = (const float*)d_in[3];
  const float* qb    = (const float*)d_in[4];
  const float* kw    = (const float*)d_in[5];
  const float* kbia  = (const float*)d_in[6];
  const float* vw    = (const float*)d_in[7];
  const float* vb    = (const float*)d_in[8];
  float* out = (float*)d_out;

  // Workspace: [0, 32M) normed fp16 [8192][2048]; [32M, 56M) W fp16 [3][2048][2048]
  char* ws = (char*)d_ws;
  _Float16* Ahp = (_Float16*)(ws);
  _Float16* Whp = (_Float16*)(ws + (size_t)MTOT * HD * 2);

  (void)hipFuncSetAttribute((const void*)qkv_gemm_kernel,
                            hipFuncAttributeMaxDynamicSharedMemorySize, 65536);

  ln_f16_kernel<<<MTOT, 256, 0, stream>>>(x, gamma, beta, Ahp);
  w_f16_kernel<<<dim3(1024, 3), 256, 0, stream>>>(qw, kw, vw, Whp);
  qkv_gemm_kernel<<<dim3(NTOT / 256, MTOT / 256), 512, 65536, stream>>>(
      Ahp, Whp, qb, kbia, vb, out);
}

// Round 6
// 266.332 us; speedup vs baseline: 7.4570x; 7.4570x over previous
//
#include <hip/hip_runtime.h>
#include <hip/hip_bf16.h>

// Fused LayerNorm + QKV projection for B=4, S=2048, H=2048 (fp32 in/out).
//
// Round 6: round-3 structure (256x256, BK=64, 8 waves, 128 KiB LDS dbuf,
// counted vmcnt(6)) with the phase sync relaxed: ONE s_barrier per phase,
// no lgkmcnt(0)+sched_barrier fence before MFMA (compiler emits fine-grained
// per-use lgkm waits), post-MFMA lgkmcnt(0) preserves the WAR guarantee.
// Round 5's launch_bounds(512,4) spill disaster reverted to (512,2).

#define HD   2048            // hidden dim (K)
#define MTOT 8192            // B*S rows
#define NTOT 6144            // 3*H packed output cols
#define NIT  16              // iterations (2 K-tiles of BK=64 each)

typedef __attribute__((ext_vector_type(8))) _Float16 f16x8;   // 4 VGPR
typedef __attribute__((ext_vector_type(4))) _Float16 f16x4;
typedef __attribute__((ext_vector_type(4))) float f32x4;

// ---------------------------------------------------------------------------
// Kernel 1: LayerNorm -> fp16.  One block per row, 256 threads, 8 elems each.
// ---------------------------------------------------------------------------
__global__ __launch_bounds__(256) void ln_f16_kernel(
    const float* __restrict__ x, const float* __restrict__ gamma,
    const float* __restrict__ beta, _Float16* __restrict__ hi) {
  const int row = blockIdx.x;
  const float* xr = x + (size_t)row * HD;
  const int t = threadIdx.x;

  float4 v0 = reinterpret_cast<const float4*>(xr)[t * 2];
  float4 v1 = reinterpret_cast<const float4*>(xr)[t * 2 + 1];
  float xs[8] = {v0.x, v0.y, v0.z, v0.w, v1.x, v1.y, v1.z, v1.w};

  float s = 0.f, q = 0.f;
#pragma unroll
  for (int j = 0; j < 8; ++j) { s += xs[j]; q += xs[j] * xs[j]; }
#pragma unroll
  for (int off = 32; off; off >>= 1) {
    s += __shfl_down(s, off);
    q += __shfl_down(q, off);
  }
  __shared__ float red[8];
  const int wid = t >> 6, lane = t & 63;
  if (lane == 0) { red[wid] = s; red[4 + wid] = q; }
  __syncthreads();
  s = red[0] + red[1] + red[2] + red[3];
  q = red[4] + red[5] + red[6] + red[7];
  const float mu  = s * (1.f / HD);
  const float var = q * (1.f / HD) - mu * mu;
  const float rs  = rsqrtf(var + 1e-5f);

  float4 g0 = reinterpret_cast<const float4*>(gamma)[t * 2];
  float4 g1 = reinterpret_cast<const float4*>(gamma)[t * 2 + 1];
  float4 b0 = reinterpret_cast<const float4*>(beta)[t * 2];
  float4 b1 = reinterpret_cast<const float4*>(beta)[t * 2 + 1];
  float gs[8] = {g0.x, g0.y, g0.z, g0.w, g1.x, g1.y, g1.z, g1.w};
  float bs[8] = {b0.x, b0.y, b0.z, b0.w, b1.x, b1.y, b1.z, b1.w};

  f16x8 hv;
#pragma unroll
  for (int j = 0; j < 8; ++j) {
    float y = (xs[j] - mu) * rs * gs[j] + bs[j];
    hv[j] = (_Float16)y;
  }
  *reinterpret_cast<f16x8*>(&hi[(size_t)row * HD + t * 8]) = hv;
}

// ---------------------------------------------------------------------------
// Kernel 2: weights -> fp16 (q, k, v stacked).
// ---------------------------------------------------------------------------
__global__ __launch_bounds__(256) void w_f16_kernel(
    const float* __restrict__ qw, const float* __restrict__ kw,
    const float* __restrict__ vw, _Float16* __restrict__ hi) {
  const int m = blockIdx.y;
  const float* src = (m == 0) ? qw : (m == 1) ? kw : vw;
  const size_t base = (size_t)m * HD * HD;
  const int total4 = HD * HD / 4;
  for (int i = blockIdx.x * blockDim.x + threadIdx.x; i < total4;
       i += gridDim.x * blockDim.x) {
    float4 v = reinterpret_cast<const float4*>(src)[i];
    f16x4 hv;
    hv[0] = (_Float16)v.x; hv[1] = (_Float16)v.y;
    hv[2] = (_Float16)v.z; hv[3] = (_Float16)v.w;
    *reinterpret_cast<f16x4*>(&hi[base + (size_t)i * 4]) = hv;
  }
}

// ---------------------------------------------------------------------------
// Kernel 3: 256x256 8-phase fp16 GEMM, relaxed sync.
// out[m][n] = sum_k A[m][k] * W_p[n][k] + bias_p[n]
//
// LDS (128 KiB, f16 units): A bufs at {0, 16384}, B bufs at {32768, 49152}.
// Buffer = 8 kb-planes x 256 rows x 8 f16 (chunk (kb,row) = X[row][k0+kb*8..]);
// linear for global_load_lds, conflict-free ds_read_b128 (0 measured r1-r3).
//
// Phase = [stage issue][ds_reads][16 MFMA][lgkmcnt(0)][vm guard?][s_barrier].
// - No pre-MFMA drain: compiler emits per-use lgkm waits, so MFMA overlaps
//   the wave's outstanding reads and waves slip within a phase.
// - Post-MFMA lgkmcnt(0) is ~free (reads consumed) and guarantees WAR: all
//   reads of a region complete before the wave's barrier; the region's
//   overwrite is issued only after that barrier.
// Stage slots + vmcnt(6) ledger identical to round 3 (passed):
//   p0: buf1.A-mh1<-kt2i+1 | p1: buf0.B-h0<-kt2i+2 | p2: buf0.B-h1 |
//   p3: buf0.A-mh0 +VM6[buf1 landed] | p4: buf0.A-mh1 | p5: buf1.B-h0<-kt2i+3 |
//   p6: buf1.B-h1 | p7: buf1.A-mh0 +VM6[buf0 landed]
// ---------------------------------------------------------------------------
__device__ __forceinline__ void gload16(const _Float16* g, _Float16* l) {
  __builtin_amdgcn_global_load_lds(
      (const __attribute__((address_space(1))) void*)g,
      (__attribute__((address_space(3))) void*)l, 16, 0, 0);
}

#define BAR()   asm volatile("s_barrier" ::: "memory")
#define LGKM0() asm volatile("s_waitcnt lgkmcnt(0)" ::: "memory")
#define VM6()   asm volatile("s_waitcnt vmcnt(6)" ::: "memory")
#define VM0()   asm volatile("s_waitcnt vmcnt(0)" ::: "memory")

#define LA(BUF, X, MH, KS) \
  (*(const f16x8*)(lds + (BUF)*16384 + rA + (KS)*8192 + (MH)*512 + (X)*128))
#define LB(BUF, NR, KS) \
  (*(const f16x8*)(lds + 32768 + (BUF)*16384 + rB + (KS)*8192 + (NR)*128))

#define BLOAD(BUF) do { \
    bfr[0][0]=LB(BUF,0,0); bfr[1][0]=LB(BUF,1,0); \
    bfr[2][0]=LB(BUF,2,0); bfr[3][0]=LB(BUF,3,0); \
    bfr[0][1]=LB(BUF,0,1); bfr[1][1]=LB(BUF,1,1); \
    bfr[2][1]=LB(BUF,2,1); bfr[3][1]=LB(BUF,3,1); \
  } while (0)
#define ALOAD(BUF, MH, KS) do { \
    a0=LA(BUF,0,MH,KS); a1=LA(BUF,1,MH,KS); \
    a2=LA(BUF,2,MH,KS); a3=LA(BUF,3,MH,KS); \
  } while (0)

#define MM(MR, NR, AREG, KS) \
  acc[MR][NR] = __builtin_amdgcn_mfma_f32_16x16x32_f16( \
      AREG, bfr[NR][KS], acc[MR][NR], 0, 0, 0);
#define MFMAS(MH, KS) do { \
    __builtin_amdgcn_s_setprio(1); \
    MM((MH)*4+0, 0, a0, KS) MM((MH)*4+0, 1, a0, KS) \
    MM((MH)*4+0, 2, a0, KS) MM((MH)*4+0, 3, a0, KS) \
    MM((MH)*4+1, 0, a1, KS) MM((MH)*4+1, 1, a1, KS) \
    MM((MH)*4+1, 2, a1, KS) MM((MH)*4+1, 3, a1, KS) \
    MM((MH)*4+2, 0, a2, KS) MM((MH)*4+2, 1, a2, KS) \
    MM((MH)*4+2, 2, a2, KS) MM((MH)*4+2, 3, a2, KS) \
    MM((MH)*4+3, 0, a3, KS) MM((MH)*4+3, 1, a3, KS) \
    MM((MH)*4+3, 2, a3, KS) MM((MH)*4+3, 3, a3, KS) \
    __builtin_amdgcn_s_setprio(0); \
  } while (0)

__global__ __launch_bounds__(512, 2) void qkv_gemm_kernel(
    const _Float16* __restrict__ Ah, const _Float16* __restrict__ Wh,
    const float* __restrict__ qb, const float* __restrict__ kb,
    const float* __restrict__ vb, float* __restrict__ out) {
  extern __shared__ _Float16 lds[];   // 131072 B

  const int t    = threadIdx.x;
  const int lane = t & 63;
  const int wid  = t >> 6;            // 0..7
  const int wm   = wid >> 2;          // 0..1 (M)
  const int wn   = wid & 3;           // 0..3 (N)
  const int fr   = lane & 15;
  const int fq   = lane >> 4;

  const int n0  = blockIdx.x * 256;
  const int m0  = blockIdx.y * 256;
  const int p   = n0 >> 11;
  const int ln0 = n0 & (HD - 1);
  const _Float16* Ag  = Ah + (size_t)m0 * HD;
  const _Float16* Bgp = Wh + (size_t)p * HD * HD + (size_t)ln0 * HD;
  const float* bias = (p == 0) ? qb : (p == 1) ? kb : vb;

  // staging invariants: wave-linear dest (chunk = kb0*256 + rowbase + lane)
  const int kb0     = t >> 7;                         // 0..3
  const int rowbase = (t & 63) + ((t & 64) << 1);     // lane + (wid&1)*128
  const size_t goff = (size_t)rowbase * HD + kb0 * 8; // global f16 offset
  const int ldsC    = kb0 * 256 + rowbase;            // lds chunk

  // fragment-read invariants (f16 offsets within a buffer)
  const int rA = fq * 2048 + wm * 1024 + fr * 8;
  const int rB = fq * 2048 + wn * 512 + fr * 8;

  auto stA = [&](int buf, int hf, int kt) {
    const _Float16* g = Ag + goff + (size_t)(hf * 64) * HD + kt * 64;
    _Float16* l = lds + buf * 16384 + (ldsC + hf * 64) * 8;
    gload16(g, l); gload16(g + 32, l + 8192);
  };
  auto stB = [&](int buf, int hf, int kt) {
    const _Float16* g = Bgp + goff + (size_t)(hf * 64) * HD + kt * 64;
    _Float16* l = lds + 32768 + buf * 16384 + (ldsC + hf * 64) * 8;
    gload16(g, l); gload16(g + 32, l + 8192);
  };

  f32x4 acc[8][4] = {};

  // Prologue: buf0 <- K-tile 0 (4 halves), buf1 <- K-tile 1 (3 halves).
  // vmcnt(6) = 3 calls in flight -> buf0 fully landed.
  stB(0, 0, 0); stB(0, 1, 0); stA(0, 0, 0); stA(0, 1, 0);
  stB(1, 0, 1); stB(1, 1, 1); stA(1, 0, 1);
  VM6();
  BAR();

#pragma unroll 1
  for (int i = 0; i < NIT; ++i) {
    const bool nl = (i < NIT - 1);
    const int kt1 = 2 * i + 1, kt2 = 2 * i + 2, kt3 = 2 * i + 3;
    f16x8 bfr[4][2];
    f16x8 a0, a1, a2, a3;

    // ---- p0..p3: read buf0 (K-tile 2i) ----
    stA(1, 1, kt1);                           // p0
    ALOAD(0, 0, 0); BLOAD(0);
    MFMAS(0, 0);
    LGKM0(); BAR();

    if (nl) stB(0, 0, kt2);                   // p1
    ALOAD(0, 0, 1);
    MFMAS(0, 1);
    LGKM0(); BAR();

    if (nl) stB(0, 1, kt2);                   // p2
    ALOAD(0, 1, 0);
    MFMAS(1, 0);
    LGKM0(); BAR();

    if (nl) stA(0, 0, kt2);                   // p3
    ALOAD(0, 1, 1);
    MFMAS(1, 1);
    LGKM0();
    if (nl) { VM6(); } else { VM0(); }        // buf1 content landed
    BAR();

    // ---- p4..p7: read buf1 (K-tile 2i+1) ----
    if (nl) stA(0, 1, kt2);                   // p4
    ALOAD(1, 0, 0); BLOAD(1);
    MFMAS(0, 0);
    LGKM0(); BAR();

    if (nl) stB(1, 0, kt3);                   // p5
    ALOAD(1, 0, 1);
    MFMAS(0, 1);
    LGKM0(); BAR();

    if (nl) stB(1, 1, kt3);                   // p6
    ALOAD(1, 1, 0);
    MFMAS(1, 0);
    LGKM0(); BAR();

    if (nl) stA(1, 0, kt3);                   // p7
    ALOAD(1, 1, 1);
    MFMAS(1, 1);
    LGKM0();
    if (nl) { VM6(); }                        // buf0 content landed
    BAR();
  }

  // Epilogue: C/D layout col = lane&15, row = (lane>>4)*4 + reg.
  float bv[4];
#pragma unroll
  for (int nr = 0; nr < 4; ++nr)
    bv[nr] = bias[(ln0 + wn * 64 + nr * 16 + fr)];
#pragma unroll
  for (int mr = 0; mr < 8; ++mr) {
    const int r0 = m0 + wm * 128 + mr * 16 + fq * 4;
#pragma unroll
    for (int nr = 0; nr < 4; ++nr) {
      const int cg = n0 + wn * 64 + nr * 16 + fr;
      f32x4 v = acc[mr][nr];
#pragma unroll
      for (int r = 0; r < 4; ++r)
        out[(size_t)(r0 + r) * NTOT + cg] = v[r] + bv[nr];
    }
  }
}

// ---------------------------------------------------------------------------
extern "C" void kernel_launch(void* const* d_in, const int* in_sizes, int n_in,
                              void* d_out, int out_size, void* d_ws,
                              size_t ws_size, hipStream_t stream) {
  const float* x     = (const float*)d_in[0];
  const float* gamma = (const float*)d_in[1];
  const float* beta  = (const float*)d_in[2];
  const float* qw    = (const float*)d_in[3];
  const float* qb    = (const float*)d_in[4];
  const float* kw    = (const float*)d_in[5];
  const float* kbia  = (const float*)d_in[6];
  const float* vw    = (const float*)d_in[7];
  const float* vb    = (const float*)d_in[8];
  float* out = (float*)d_out;

  // Workspace: [0, 32M) normed fp16 [8192][2048]; [32M, 56M) W fp16 [3][2048][2048]
  char* ws = (char*)d_ws;
  _Float16* Ahp = (_Float16*)(ws);
  _Float16* Whp = (_Float16*)(ws + (size_t)MTOT * HD * 2);

  (void)hipFuncSetAttribute((const void*)qkv_gemm_kernel,
                            hipFuncAttributeMaxDynamicSharedMemorySize, 131072);

  ln_f16_kernel<<<MTOT, 256, 0, stream>>>(x, gamma, beta, Ahp);
  w_f16_kernel<<<dim3(1024, 3), 256, 0, stream>>>(qw, kw, vw, Whp);
  qkv_gemm_kernel<<<dim3(NTOT / 256, MTOT / 256), 512, 131072, stream>>>(
      Ahp, Whp, qb, kbia, vb, out);
}